// Round 13
// baseline (253.524 us; speedup 1.0000x reference)
//
#include <hip/hip_runtime.h>
#include <hip/hip_bf16.h>

#define N_NODES 65536
#define N_EDGES 524288

typedef __attribute__((ext_vector_type(8))) short bf16x8;
typedef __attribute__((ext_vector_type(4))) float f32x4;

__device__ __forceinline__ float bf2f(unsigned short u) {
    union { unsigned int i; float f; } v;
    v.i = ((unsigned int)u) << 16;
    return v.f;
}
__device__ __forceinline__ unsigned short f2bf(float f) {
    union { float f; unsigned int i; } v;
    v.f = f;
    unsigned int r = v.i + 0x7fff + ((v.i >> 16) & 1);  // round-to-nearest-even
    return (unsigned short)(r >> 16);
}

// ---------------- init: deg=1 (self-loop), cnt=0, logits=0 --------------------
__global__ void init_k(float* __restrict__ deg, int* __restrict__ cnt,
                       float* __restrict__ logits) {
    int i = blockIdx.x * 256 + threadIdx.x;
    deg[i] = 1.0f;
    cnt[i] = 0;
    if (i < 512) logits[i] = 0.0f;
}
__global__ void deg_cnt_k(const int* __restrict__ dst, const float* __restrict__ w,
                          float* __restrict__ deg, int* __restrict__ cnt) {
    int e = blockIdx.x * 256 + threadIdx.x;
    int d = dst[e];
    atomicAdd(&deg[d], w[e]);
    atomicAdd(&cnt[d], 1);
}

// ------- hierarchical exclusive scan of cnt[65536] -> rp, cursor, dinv --------
__global__ __launch_bounds__(256) void scan1_k(const int* __restrict__ cnt,
                                               int* __restrict__ rp,
                                               int* __restrict__ bsum) {
    __shared__ int s[256];
    int t = threadIdx.x, g = blockIdx.x * 256 + t;
    int v = cnt[g];
    s[t] = v;
    __syncthreads();
    for (int d = 1; d < 256; d <<= 1) {
        int u = (t >= d) ? s[t - d] : 0;
        __syncthreads();
        s[t] += u;
        __syncthreads();
    }
    rp[g] = s[t] - v;
    if (t == 255) bsum[blockIdx.x] = s[255];
}
__global__ __launch_bounds__(256) void scan2_k(int* __restrict__ bsum,
                                               int* __restrict__ rp) {
    __shared__ int s[256];
    int t = threadIdx.x;
    int v = bsum[t];
    s[t] = v;
    __syncthreads();
    for (int d = 1; d < 256; d <<= 1) {
        int u = (t >= d) ? s[t - d] : 0;
        __syncthreads();
        s[t] += u;
        __syncthreads();
    }
    bsum[t] = s[t] - v;
    if (t == 255) rp[65536] = s[255];
}
__global__ __launch_bounds__(256) void scan3_k(int* __restrict__ rp,
                                               const int* __restrict__ bsum,
                                               int* __restrict__ cursor,
                                               const float* __restrict__ deg,
                                               float* __restrict__ dinv) {
    int t = threadIdx.x, g = blockIdx.x * 256 + t;
    int r = rp[g] + bsum[blockIdx.x];
    rp[g] = r;
    cursor[g] = r;
    dinv[g] = rsqrtf(deg[g]);
}

// ------- scatter edges into dst-sorted CSR order, packed (src, coef) ----------
__global__ void scatter_k(const int* __restrict__ src, const int* __restrict__ dst,
                          const float* __restrict__ w, const float* __restrict__ dinv,
                          int* __restrict__ cursor, uint2* __restrict__ ep) {
    int e = blockIdx.x * 256 + threadIdx.x;
    int s = src[e], d = dst[e];
    int pos = atomicAdd(&cursor[d], 1);
    uint2 p;
    p.x = (unsigned int)s;
    p.y = __float_as_uint(dinv[s] * w[e] * dinv[d]);
    ep[pos] = p;
}

// -------- prep: f2b(x) | fragment-pack wc1,wc2 | wcomb (packed) ---------------
// Packed fragment order for weights (N x K, (out,in)): entry
//   Bpk[((nb*nkt + kt)*64 + kh*16 + nl)*8 + ke]  = W[nb*16+nl][kt*32+kh*8+ke]
// so a wave's B-fragment load is 64 lanes x contiguous 16B = one 1KB burst.
// blocks [0,8192): x ; [8192,8704): wc1 pack ; [8704,8768): wc2 pack ;
// [8768,9024): wcomb (computed, packed, nkt=4)
__global__ void prep_k(const float* __restrict__ x, __hip_bfloat16* __restrict__ xbf,
                       const float* __restrict__ wc1, __hip_bfloat16* __restrict__ wc1pk,
                       const float* __restrict__ wc2, __hip_bfloat16* __restrict__ wc2pk,
                       const float* __restrict__ w1, const float* __restrict__ wg,
                       __hip_bfloat16* __restrict__ WTpk) {
    int bid = blockIdx.x;
    if (bid < 8192) {
        int i = bid * 1024 + threadIdx.x * 4;
        float4 v = *(const float4*)(x + i);
        alignas(8) __hip_bfloat16 tmp[4] = {__float2bfloat16(v.x), __float2bfloat16(v.y),
                                            __float2bfloat16(v.z), __float2bfloat16(v.w)};
        *(ushort4*)((unsigned short*)xbf + i) = *(const ushort4*)tmp;
    } else if (bid < 8768) {
        const float* W;
        __hip_bfloat16* outp;
        int t, K, nkt;
        if (bid < 8704) { W = wc1; outp = wc1pk; t = (bid - 8192) * 256 + threadIdx.x; K = 2048; nkt = 64; }
        else            { W = wc2; outp = wc2pk; t = (bid - 8704) * 256 + threadIdx.x; K = 512;  nkt = 16; }
        int l = t & 63, grp = t >> 6;
        int kt = grp % nkt, nb = grp / nkt;
        int n = nb * 16 + (l & 15);
        int k0 = kt * 32 + (l >> 4) * 8;
        const float* src = W + (size_t)n * K + k0;
        alignas(16) __hip_bfloat16 tmp[8];
#pragma unroll
        for (int e = 0; e < 8; ++e) tmp[e] = __float2bfloat16(src[e]);
        *(ushort4*)((unsigned short*)outp + (size_t)t * 8)     = *(const ushort4*)tmp;
        *(ushort4*)((unsigned short*)outp + (size_t)t * 8 + 4) = *(const ushort4*)(tmp + 4);
    } else {
        int t = (bid - 8768) * 256 + threadIdx.x;  // 512*128
        int f = t >> 7, c = t & 127;
        float s = 0.f;
#pragma unroll 8
        for (int m = 0; m < 128; ++m) s += w1[c * 128 + m] * wg[m * 512 + f];
        // packed index, nkt = 4
        int pk = ((((f >> 4) * 4 + (c >> 5)) * 64 + ((c >> 3) & 3) * 16 + (f & 15)) * 8) + (c & 7);
        WTpk[pk] = __float2bfloat16(s);
    }
}

// ---------------- gather SpMM, 4-deep ILP pipeline -----------------------------
__global__ __launch_bounds__(256) void gather_k(const int* __restrict__ rp,
                                                const uint2* __restrict__ ep,
                                                const unsigned short* __restrict__ xbf,
                                                const float* __restrict__ dinv,
                                                __hip_bfloat16* __restrict__ ybf) {
    int n = (blockIdx.x * 256 + threadIdx.x) >> 6;
    int lane = threadIdx.x & 63;
    int beg = rp[n], end = rp[n + 1];
    float di = dinv[n];
    float accx, accy;
    {
        unsigned int u = *(const unsigned int*)(xbf + (size_t)n * 128 + lane * 2);
        float c = di * di;
        accx = c * bf2f((unsigned short)(u & 0xffff));
        accy = c * bf2f((unsigned short)(u >> 16));
    }
    int i = beg;
    for (; i + 4 <= end; i += 4) {
        uint2 p0 = ep[i], p1 = ep[i + 1], p2 = ep[i + 2], p3 = ep[i + 3];
        unsigned int u0 = *(const unsigned int*)(xbf + (size_t)p0.x * 128 + lane * 2);
        unsigned int u1 = *(const unsigned int*)(xbf + (size_t)p1.x * 128 + lane * 2);
        unsigned int u2 = *(const unsigned int*)(xbf + (size_t)p2.x * 128 + lane * 2);
        unsigned int u3 = *(const unsigned int*)(xbf + (size_t)p3.x * 128 + lane * 2);
        float c0 = __uint_as_float(p0.y), c1 = __uint_as_float(p1.y);
        float c2 = __uint_as_float(p2.y), c3 = __uint_as_float(p3.y);
        accx += c0 * bf2f((unsigned short)(u0 & 0xffff));
        accy += c0 * bf2f((unsigned short)(u0 >> 16));
        accx += c1 * bf2f((unsigned short)(u1 & 0xffff));
        accy += c1 * bf2f((unsigned short)(u1 >> 16));
        accx += c2 * bf2f((unsigned short)(u2 & 0xffff));
        accy += c2 * bf2f((unsigned short)(u2 >> 16));
        accx += c3 * bf2f((unsigned short)(u3 & 0xffff));
        accy += c3 * bf2f((unsigned short)(u3 >> 16));
    }
    for (; i < end; ++i) {
        uint2 p = ep[i];
        unsigned int u = *(const unsigned int*)(xbf + (size_t)p.x * 128 + lane * 2);
        float c = __uint_as_float(p.y);
        accx += c * bf2f((unsigned short)(u & 0xffff));
        accy += c * bf2f((unsigned short)(u >> 16));
    }
    alignas(4) __hip_bfloat16 o[2] = {__float2bfloat16(accx), __float2bfloat16(accy)};
    *(unsigned int*)((unsigned short*)ybf + (size_t)n * 128 + lane * 2) =
        *(const unsigned int*)o;
}

// ---------------- async global -> LDS, 16B per lane ---------------------------
__device__ __forceinline__ void gll16(const void* g, void* l) {
    __builtin_amdgcn_global_load_lds(
        (const __attribute__((address_space(1))) void*)g,
        (__attribute__((address_space(3))) void*)l, 16, 0, 0);
}

// ---------------- bf16 MFMA GEMM: A via LDS (4-buf), B packed -> registers ----
// C = act(A @ Bpk + bias). A staged via gll16 (conflict-free swizzle, verified
// 0 conflicts R11/R12); B loaded as coalesced 1KB fragment bursts from the
// packed layout straight into registers (double-buffered b0/b1, K-loop
// unrolled x2 so indices are static). Counted vmcnt(6/4/0); one barrier per
// K-step (4 A-buffers make WAR safe). LDS = 32KB.
// SWAPPED-OPERAND mfma: lane holds 4 consecutive output cols of one row.
// ACT: 1 relu, 2 tanh(fast). OUT_MODE: 1 bf16 rm, 2 bf16 permute, 3 final dot.
// SWIZ_NTX>0: XCD-chunked 1D grid. Requires nk = K/32 even, >= 4.
template <int ACT, int OUT_MODE, int SWIZ_NTX>
__global__ __launch_bounds__(256) void gemm_mfma_k(
    const __hip_bfloat16* __restrict__ A, const __hip_bfloat16* __restrict__ Bpk,
    const float* __restrict__ bias, void* __restrict__ Cout,
    const float* __restrict__ wlin, int M, int N, int K) {
    __shared__ char lds[32768];  // 4 bufs x A-tile 8KB

    const int tid = threadIdx.x;
    const int lane = tid & 63, wid = tid >> 6;
    int bx, by;
    if (SWIZ_NTX > 0) {
        int orig = blockIdx.x;
        int per = gridDim.x / (8 * SWIZ_NTX);
        int xcd = orig & 7, k = orig >> 3;
        by = xcd * per + k / SWIZ_NTX;
        bx = k % SWIZ_NTX;
    } else {
        bx = blockIdx.x;
        by = blockIdx.y;
    }
    const int bm = by * 128, bn = bx * 128;
    const int wr = wid >> 1, wc = wid & 1;
    const int nk = K >> 5;

    // A staging: row srow, physical slot lane&3; source pre-swizzled so
    // physical slot p at row r holds logical p ^ ((r>>1)&3).
    const int srow = wid * 16 + (lane >> 2);
    const int skcol = (((lane & 3) ^ ((lane >> 3) & 3))) * 8;
    const __hip_bfloat16* Abase = A + (size_t)(bm + srow) * K + skcol;
    const int ldso = wid * 1024;

    // B packed: per-fragment base, one 1KB coalesced burst per (j, kt)
    const __hip_bfloat16* Bp[4];
#pragma unroll
    for (int j = 0; j < 4; ++j)
        Bp[j] = Bpk + ((size_t)((bn >> 4) + wc * 4 + j) * nk) * 512 + lane * 8;

    f32x4 acc[4][4] = {};
    const int lrow = lane & 15;
    const int lkb = (((lane >> 4) ^ ((lane >> 1) & 3)) << 4);

    auto stageA = [&](int buf, int kt) {
        char* la = lds + buf * 8192;
        gll16(Abase + kt * 32,                  la + ldso);
        gll16(Abase + kt * 32 + (size_t)64 * K, la + 4096 + ldso);
    };

    bf16x8 b0[4], b1[4];
    stageA(0, 0);
    stageA(1, 1);
#pragma unroll
    for (int j = 0; j < 4; ++j) b0[j] = *(const bf16x8*)(Bp[j]);

#define GEMM_HALF(KT, BREG)                                                     \
    {                                                                           \
        const char* la = lds + ((KT) & 3) * 8192;                               \
        bf16x8 af[4];                                                           \
        _Pragma("unroll")                                                       \
        for (int i = 0; i < 4; ++i)                                             \
            af[i] = *(const bf16x8*)(la + (wr * 64 + i * 16 + lrow) * 64 + lkb);\
        __builtin_amdgcn_s_setprio(1);                                          \
        _Pragma("unroll")                                                       \
        for (int i = 0; i < 4; ++i)                                             \
            _Pragma("unroll")                                                   \
            for (int j = 0; j < 4; ++j)                                         \
                acc[i][j] = __builtin_amdgcn_mfma_f32_16x16x32_bf16(            \
                    BREG[j], af[i], acc[i][j], 0, 0, 0);                        \
        __builtin_amdgcn_s_setprio(0);                                          \
        asm volatile("" ::: "memory");                                          \
    }

    for (int kt = 0; kt < nk; kt += 2) {
        // ---- even half: uses A(kt), b0 ----
        if (kt + 2 < nk) stageA((kt + 2) & 3, kt + 2);
        if (kt + 1 < nk) {
#pragma unroll
            for (int j = 0; j < 4; ++j)
                b1[j] = *(const bf16x8*)(Bp[j] + (size_t)(kt + 1) * 512);
        }
        if (kt + 2 < nk)      asm volatile("s_waitcnt vmcnt(6)" ::: "memory");
        else if (kt + 1 < nk) asm volatile("s_waitcnt vmcnt(4)" ::: "memory");
        else                  asm volatile("s_waitcnt vmcnt(0)" ::: "memory");
        __builtin_amdgcn_s_barrier();
        asm volatile("" ::: "memory");
        GEMM_HALF(kt, b0);

        // ---- odd half: uses A(kt+1), b1 ----
        if (kt + 3 < nk) stageA((kt + 3) & 3, kt + 3);
        if (kt + 2 < nk) {
#pragma unroll
            for (int j = 0; j < 4; ++j)
                b0[j] = *(const bf16x8*)(Bp[j] + (size_t)(kt + 2) * 512);
        }
        if (kt + 3 < nk)      asm volatile("s_waitcnt vmcnt(6)" ::: "memory");
        else if (kt + 2 < nk) asm volatile("s_waitcnt vmcnt(4)" ::: "memory");
        else                  asm volatile("s_waitcnt vmcnt(0)" ::: "memory");
        __builtin_amdgcn_s_barrier();
        asm volatile("" ::: "memory");
        GEMM_HALF(kt + 1, b1);
    }
#undef GEMM_HALF

    const int l15 = lane & 15, lhi = lane >> 4;

    if (OUT_MODE == 3) {
        // row m = bm+wr*64+i*16+l15 ; col p = bn+wc*64+j*16+lhi*4+r
        float p0 = 0.f, p1 = 0.f;
#pragma unroll
        for (int i = 0; i < 4; ++i) {
            int e = (i & 1) * 16 + l15;  // m & 31
#pragma unroll
            for (int j = 0; j < 4; ++j) {
                int n = bn + wc * 64 + j * 16 + lhi * 4;
                float4 bv = *(const float4*)(bias + n);
#pragma unroll
                for (int r = 0; r < 4; ++r) {
                    float v = fmaxf(acc[i][j][r] + ((const float*)&bv)[r], 0.f);
                    float wl = wlin[(n + r) * 32 + e];
                    if (i < 2) p0 += v * wl; else p1 += v * wl;
                }
            }
        }
#pragma unroll
        for (int off = 32; off > 0; off >>= 1) {
            p0 += __shfl_down(p0, off, 64);
            p1 += __shfl_down(p1, off, 64);
        }
        if (lane == 0) {
            int g = (bm >> 5) + wr * 2;
            atomicAdd(&((float*)Cout)[g], p0);
            atomicAdd(&((float*)Cout)[g + 1], p1);
        }
        return;
    }

#pragma unroll
    for (int i = 0; i < 4; ++i) {
        int m = bm + wr * 64 + i * 16 + l15;
#pragma unroll
        for (int j = 0; j < 4; ++j) {
            int n = bn + wc * 64 + j * 16 + lhi * 4;
            float4 bv = *(const float4*)(bias + n);
            ushort4 o;
#pragma unroll
            for (int r = 0; r < 4; ++r) {
                float v = acc[i][j][r] + ((const float*)&bv)[r];
                if (ACT == 1) v = fmaxf(v, 0.f);
                if (ACT == 2) v = 1.0f - 2.0f / (__expf(2.0f * v) + 1.0f);
                ((unsigned short*)&o)[r] = f2bf(v);
            }
            if (OUT_MODE == 1) {
                *(ushort4*)((unsigned short*)Cout + (size_t)m * N + n) = o;
            } else {
                size_t prow = (size_t)(((m >> 7) << 5) | (m & 31));
                size_t idx = prow * 2048 + (size_t)(((m >> 5) & 3) * 512 + n);
                *(ushort4*)((unsigned short*)Cout + idx) = o;
            }
        }
    }
}

// ---------------- sigmoid over 512 graph logits --------------------------------
__global__ void sigmoid_k(const float* __restrict__ logits,
                          const float* __restrict__ blin, float* __restrict__ out) {
    int b = blockIdx.x * 256 + threadIdx.x;
    out[b] = 1.0f / (1.0f + expf(-(logits[b] + blin[0])));
}

extern "C" void kernel_launch(void* const* d_in, const int* in_sizes, int n_in,
                              void* d_out, int out_size, void* d_ws, size_t ws_size,
                              hipStream_t stream) {
    const float* x    = (const float*)d_in[0];
    const float* eattr= (const float*)d_in[1];
    const float* w1   = (const float*)d_in[2];
    const float* wg   = (const float*)d_in[3];
    const float* bg   = (const float*)d_in[4];
    const float* wc1  = (const float*)d_in[5];
    const float* bc1  = (const float*)d_in[6];
    const float* wc2  = (const float*)d_in[7];
    const float* bc2  = (const float*)d_in[8];
    const float* wlin = (const float*)d_in[9];
    const float* blin = (const float*)d_in[10];
    const int*   ei   = (const int*)d_in[11];
    const int* esrc = ei;
    const int* edst = ei + N_EDGES;
    float* out = (float*)d_out;

    // workspace layout (bytes, 16B aligned)
    char* ws = (char*)d_ws;
    float*          dinv   = (float*)(ws + 0);          // 262144
    int*            cnt    = (int*)(ws + 262144);       // 262144
    int*            rp     = (int*)(ws + 524288);       // 262160 (65537 ints)
    int*            cursor = (int*)(ws + 786688);       // 262144
    uint2*          ep     = (uint2*)(ws + 1048832);    // 4194304
    __hip_bfloat16* WTpk   = (__hip_bfloat16*)(ws + 5243136);   // 131072
    __hip_bfloat16* ybf    = (__hip_bfloat16*)(ws + 5374208);   // 16777216
    __hip_bfloat16* V      = (__hip_bfloat16*)(ws + 22151424);  // 67108864
    __hip_bfloat16* act1   = (__hip_bfloat16*)(ws + 89260288);  // 16777216
    __hip_bfloat16* wc1pk  = (__hip_bfloat16*)(ws + 106037504); // 2097152
    __hip_bfloat16* wc2pk  = (__hip_bfloat16*)(ws + 108134656); // 262144
    __hip_bfloat16* xbf    = (__hip_bfloat16*)(ws + 108396800); // 16777216
    float*          logits = (float*)(ws + 125174016);  // 2048
    int*            bsum   = (int*)(ws + 125176064);    // 1024
    if (ws_size < (size_t)125177088) return;

    // 1) init
    init_k<<<N_NODES / 256, 256, 0, stream>>>(dinv, cnt, logits);

    // 2) degree + in-degree counts
    deg_cnt_k<<<N_EDGES / 256, 256, 0, stream>>>(edst, eattr, dinv, cnt);

    // 3) hierarchical scan
    scan1_k<<<256, 256, 0, stream>>>(cnt, rp, bsum);
    scan2_k<<<1, 256, 0, stream>>>(bsum, rp);
    scan3_k<<<256, 256, 0, stream>>>(rp, bsum, cursor, dinv, dinv);

    // 4) scatter edges into CSR, packed 8B records
    scatter_k<<<N_EDGES / 256, 256, 0, stream>>>(esrc, edst, eattr, dinv,
                                                 cursor, ep);

    // 5) prep: x->bf16, weights -> packed fragment order
    prep_k<<<9024, 256, 0, stream>>>(x, xbf, wc1, wc1pk, wc2, wc2pk, w1, wg, WTpk);

    // 6) gather SpMM on bf16 x -> ybf (4-deep ILP)
    gather_k<<<N_NODES / 4, 256, 0, stream>>>(rp, ep,
                                              (const unsigned short*)xbf, dinv, ybf);

    // 7) h2 = tanh(y @ W_comb + b_gcn) -> V (bf16, rearranged layout)
    gemm_mfma_k<2, 2, 0><<<dim3(4, 512), 256, 0, stream>>>(
        ybf, WTpk, bg, V, nullptr, 65536, 512, 128);

    // 8) cnn1: act1 = relu(V @ wc1^T + bc1), XCD-swizzled 1D grid
    gemm_mfma_k<1, 1, 4><<<512, 256, 0, stream>>>(
        V, wc1pk, bc1, act1, nullptr, 16384, 512, 2048);

    // 9) cnn2 + final dot fused
    gemm_mfma_k<1, 3, 0><<<dim3(2, 128), 256, 0, stream>>>(
        act1, wc2pk, bc2, logits, wlin, 16384, 256, 512);

    // 10) sigmoid
    sigmoid_k<<<2, 256, 0, stream>>>(logits, blin, out);
}

// Round 14
// 252.173 us; speedup vs baseline: 1.0054x; 1.0054x over previous
//
#include <hip/hip_runtime.h>
#include <hip/hip_bf16.h>

#define N_NODES 65536
#define N_EDGES 524288

typedef __attribute__((ext_vector_type(8))) short bf16x8;
typedef __attribute__((ext_vector_type(4))) float f32x4;

__device__ __forceinline__ float bf2f(unsigned short u) {
    union { unsigned int i; float f; } v;
    v.i = ((unsigned int)u) << 16;
    return v.f;
}
__device__ __forceinline__ unsigned short f2bf(float f) {
    union { float f; unsigned int i; } v;
    v.f = f;
    unsigned int r = v.i + 0x7fff + ((v.i >> 16) & 1);  // round-to-nearest-even
    return (unsigned short)(r >> 16);
}

// ---------------- init: deg=1 (self-loop), cnt=0, logits=0 --------------------
__global__ void init_k(float* __restrict__ deg, int* __restrict__ cnt,
                       float* __restrict__ logits) {
    int i = blockIdx.x * 256 + threadIdx.x;
    deg[i] = 1.0f;
    cnt[i] = 0;
    if (i < 512) logits[i] = 0.0f;
}
__global__ void deg_cnt_k(const int* __restrict__ dst, const float* __restrict__ w,
                          float* __restrict__ deg, int* __restrict__ cnt) {
    int e = blockIdx.x * 256 + threadIdx.x;
    int d = dst[e];
    atomicAdd(&deg[d], w[e]);
    atomicAdd(&cnt[d], 1);
}

// ------- hierarchical exclusive scan of cnt[65536] -> rp, cursor, dinv --------
__global__ __launch_bounds__(256) void scan1_k(const int* __restrict__ cnt,
                                               int* __restrict__ rp,
                                               int* __restrict__ bsum) {
    __shared__ int s[256];
    int t = threadIdx.x, g = blockIdx.x * 256 + t;
    int v = cnt[g];
    s[t] = v;
    __syncthreads();
    for (int d = 1; d < 256; d <<= 1) {
        int u = (t >= d) ? s[t - d] : 0;
        __syncthreads();
        s[t] += u;
        __syncthreads();
    }
    rp[g] = s[t] - v;
    if (t == 255) bsum[blockIdx.x] = s[255];
}
__global__ __launch_bounds__(256) void scan2_k(int* __restrict__ bsum,
                                               int* __restrict__ rp) {
    __shared__ int s[256];
    int t = threadIdx.x;
    int v = bsum[t];
    s[t] = v;
    __syncthreads();
    for (int d = 1; d < 256; d <<= 1) {
        int u = (t >= d) ? s[t - d] : 0;
        __syncthreads();
        s[t] += u;
        __syncthreads();
    }
    bsum[t] = s[t] - v;
    if (t == 255) rp[65536] = s[255];
}
__global__ __launch_bounds__(256) void scan3_k(int* __restrict__ rp,
                                               const int* __restrict__ bsum,
                                               int* __restrict__ cursor,
                                               const float* __restrict__ deg,
                                               float* __restrict__ dinv) {
    int t = threadIdx.x, g = blockIdx.x * 256 + t;
    int r = rp[g] + bsum[blockIdx.x];
    rp[g] = r;
    cursor[g] = r;
    dinv[g] = rsqrtf(deg[g]);
}

// ------- scatter edges into dst-sorted CSR order, packed (src, coef) ----------
__global__ void scatter_k(const int* __restrict__ src, const int* __restrict__ dst,
                          const float* __restrict__ w, const float* __restrict__ dinv,
                          int* __restrict__ cursor, uint2* __restrict__ ep) {
    int e = blockIdx.x * 256 + threadIdx.x;
    int s = src[e], d = dst[e];
    int pos = atomicAdd(&cursor[d], 1);
    uint2 p;
    p.x = (unsigned int)s;
    p.y = __float_as_uint(dinv[s] * w[e] * dinv[d]);
    ep[pos] = p;
}

// -------- prep: f2b(x) | fragment-pack wc1,wc2 | wcomb (packed) ---------------
// Packed fragment order for weights (N x K, (out,in)): entry
//   Bpk[((nb*nkt + kt)*64 + kh*16 + nl)*8 + ke]  = W[nb*16+nl][kt*32+kh*8+ke]
__global__ void prep_k(const float* __restrict__ x, __hip_bfloat16* __restrict__ xbf,
                       const float* __restrict__ wc1, __hip_bfloat16* __restrict__ wc1pk,
                       const float* __restrict__ wc2, __hip_bfloat16* __restrict__ wc2pk,
                       const float* __restrict__ w1, const float* __restrict__ wg,
                       __hip_bfloat16* __restrict__ WTpk) {
    int bid = blockIdx.x;
    if (bid < 8192) {
        int i = bid * 1024 + threadIdx.x * 4;
        float4 v = *(const float4*)(x + i);
        alignas(8) __hip_bfloat16 tmp[4] = {__float2bfloat16(v.x), __float2bfloat16(v.y),
                                            __float2bfloat16(v.z), __float2bfloat16(v.w)};
        *(ushort4*)((unsigned short*)xbf + i) = *(const ushort4*)tmp;
    } else if (bid < 8768) {
        const float* W;
        __hip_bfloat16* outp;
        int t, K, nkt;
        if (bid < 8704) { W = wc1; outp = wc1pk; t = (bid - 8192) * 256 + threadIdx.x; K = 2048; nkt = 64; }
        else            { W = wc2; outp = wc2pk; t = (bid - 8704) * 256 + threadIdx.x; K = 512;  nkt = 16; }
        int l = t & 63, grp = t >> 6;
        int kt = grp % nkt, nb = grp / nkt;
        int n = nb * 16 + (l & 15);
        int k0 = kt * 32 + (l >> 4) * 8;
        const float* src = W + (size_t)n * K + k0;
        alignas(16) __hip_bfloat16 tmp[8];
#pragma unroll
        for (int e = 0; e < 8; ++e) tmp[e] = __float2bfloat16(src[e]);
        *(ushort4*)((unsigned short*)outp + (size_t)t * 8)     = *(const ushort4*)tmp;
        *(ushort4*)((unsigned short*)outp + (size_t)t * 8 + 4) = *(const ushort4*)(tmp + 4);
    } else {
        int t = (bid - 8768) * 256 + threadIdx.x;  // 512*128
        int f = t >> 7, c = t & 127;
        float s = 0.f;
#pragma unroll 8
        for (int m = 0; m < 128; ++m) s += w1[c * 128 + m] * wg[m * 512 + f];
        int pk = ((((f >> 4) * 4 + (c >> 5)) * 64 + ((c >> 3) & 3) * 16 + (f & 15)) * 8) + (c & 7);
        WTpk[pk] = __float2bfloat16(s);
    }
}

// ---------------- gather SpMM, 4-deep ILP pipeline -----------------------------
__global__ __launch_bounds__(256) void gather_k(const int* __restrict__ rp,
                                                const uint2* __restrict__ ep,
                                                const unsigned short* __restrict__ xbf,
                                                const float* __restrict__ dinv,
                                                __hip_bfloat16* __restrict__ ybf) {
    int n = (blockIdx.x * 256 + threadIdx.x) >> 6;
    int lane = threadIdx.x & 63;
    int beg = rp[n], end = rp[n + 1];
    float di = dinv[n];
    float accx, accy;
    {
        unsigned int u = *(const unsigned int*)(xbf + (size_t)n * 128 + lane * 2);
        float c = di * di;
        accx = c * bf2f((unsigned short)(u & 0xffff));
        accy = c * bf2f((unsigned short)(u >> 16));
    }
    int i = beg;
    for (; i + 4 <= end; i += 4) {
        uint2 p0 = ep[i], p1 = ep[i + 1], p2 = ep[i + 2], p3 = ep[i + 3];
        unsigned int u0 = *(const unsigned int*)(xbf + (size_t)p0.x * 128 + lane * 2);
        unsigned int u1 = *(const unsigned int*)(xbf + (size_t)p1.x * 128 + lane * 2);
        unsigned int u2 = *(const unsigned int*)(xbf + (size_t)p2.x * 128 + lane * 2);
        unsigned int u3 = *(const unsigned int*)(xbf + (size_t)p3.x * 128 + lane * 2);
        float c0 = __uint_as_float(p0.y), c1 = __uint_as_float(p1.y);
        float c2 = __uint_as_float(p2.y), c3 = __uint_as_float(p3.y);
        accx += c0 * bf2f((unsigned short)(u0 & 0xffff));
        accy += c0 * bf2f((unsigned short)(u0 >> 16));
        accx += c1 * bf2f((unsigned short)(u1 & 0xffff));
        accy += c1 * bf2f((unsigned short)(u1 >> 16));
        accx += c2 * bf2f((unsigned short)(u2 & 0xffff));
        accy += c2 * bf2f((unsigned short)(u2 >> 16));
        accx += c3 * bf2f((unsigned short)(u3 & 0xffff));
        accy += c3 * bf2f((unsigned short)(u3 >> 16));
    }
    for (; i < end; ++i) {
        uint2 p = ep[i];
        unsigned int u = *(const unsigned int*)(xbf + (size_t)p.x * 128 + lane * 2);
        float c = __uint_as_float(p.y);
        accx += c * bf2f((unsigned short)(u & 0xffff));
        accy += c * bf2f((unsigned short)(u >> 16));
    }
    alignas(4) __hip_bfloat16 o[2] = {__float2bfloat16(accx), __float2bfloat16(accy)};
    *(unsigned int*)((unsigned short*)ybf + (size_t)n * 128 + lane * 2) =
        *(const unsigned int*)o;
}

// ---------------- async global -> LDS, 16B per lane ---------------------------
__device__ __forceinline__ void gll16(const void* g, void* l) {
    __builtin_amdgcn_global_load_lds(
        (const __attribute__((address_space(1))) void*)g,
        (__attribute__((address_space(3))) void*)l, 16, 0, 0);
}

// ---------------- bf16 MFMA GEMM: 64x128 tile, 4 waves x (64x32) --------------
// Occupancy-oriented geometry: grid has 2x the blocks of the 128x128 version
// (4 blocks/CU on cnn1 -> 4 waves/SIMD; latency hiding was the R10-R13
// invariant). A staged via gll16 into 4 x 4KB LDS buffers (conflict-free
// swizzle, verified 0 conflicts); B from packed fragment layout straight into
// registers (b0/b1 double-buffer, K-loop unrolled x2). Counted vmcnt; one
// barrier per K-step. SWAPPED-OPERAND mfma: lane holds 4 consecutive output
// cols of one row -> 8B ushort4 stores.
// ACT: 1 relu, 2 tanh(fast). OUT_MODE: 1 bf16 rm, 2 bf16 permute, 3 final dot.
// SWIZ_NTX>0: XCD-chunked 1D grid. Requires nk = K/32 even, >= 4.
template <int ACT, int OUT_MODE, int SWIZ_NTX>
__global__ __launch_bounds__(256) void gemm_mfma_k(
    const __hip_bfloat16* __restrict__ A, const __hip_bfloat16* __restrict__ Bpk,
    const float* __restrict__ bias, void* __restrict__ Cout,
    const float* __restrict__ wlin, int M, int N, int K) {
    __shared__ char lds[16384];  // 4 bufs x A-tile 4KB

    const int tid = threadIdx.x;
    const int lane = tid & 63, wid = tid >> 6;
    int bx, by;
    if (SWIZ_NTX > 0) {
        int orig = blockIdx.x;
        int per = gridDim.x / (8 * SWIZ_NTX);
        int xcd = orig & 7, k = orig >> 3;
        by = xcd * per + k / SWIZ_NTX;
        bx = k % SWIZ_NTX;
    } else {
        bx = blockIdx.x;
        by = blockIdx.y;
    }
    const int bm = by * 64, bn = bx * 128;
    const int nk = K >> 5;

    // A staging: 64 rows x 32 k = 4KB; wave wid stages rows wid*16..+15.
    // physical 16B slot lane&3 at row r holds logical slot (lane&3)^((r>>1)&3).
    const int srow = wid * 16 + (lane >> 2);
    const int skcol = (((lane & 3) ^ ((lane >> 3) & 3))) * 8;
    const __hip_bfloat16* Abase = A + (size_t)(bm + srow) * K + skcol;
    const int ldso = wid * 1024;

    // B packed: wave wid covers cols bn + wid*32 .. +31 -> 2 fragments
    const __hip_bfloat16* Bp[2];
#pragma unroll
    for (int j = 0; j < 2; ++j)
        Bp[j] = Bpk + ((size_t)((bn >> 4) + wid * 2 + j) * nk) * 512 + lane * 8;

    f32x4 acc[4][2] = {};
    const int lrow = lane & 15;
    const int lkb = (((lane >> 4) ^ ((lane >> 1) & 3)) << 4);

    auto stageA = [&](int buf, int kt) {
        gll16(Abase + kt * 32, lds + buf * 4096 + ldso);
    };

    bf16x8 b0[2], b1[2];
    stageA(0, 0);
    stageA(1, 1);
    asm volatile("" ::: "memory");
#pragma unroll
    for (int j = 0; j < 2; ++j) b0[j] = *(const bf16x8*)(Bp[j]);

#define GEMM_HALF(KT, BREG)                                                     \
    {                                                                           \
        const char* la = lds + ((KT) & 3) * 4096;                               \
        bf16x8 af[4];                                                           \
        _Pragma("unroll")                                                       \
        for (int i = 0; i < 4; ++i)                                             \
            af[i] = *(const bf16x8*)(la + (i * 16 + lrow) * 64 + lkb);          \
        __builtin_amdgcn_s_setprio(1);                                          \
        _Pragma("unroll")                                                       \
        for (int i = 0; i < 4; ++i)                                             \
            _Pragma("unroll")                                                   \
            for (int j = 0; j < 2; ++j)                                         \
                acc[i][j] = __builtin_amdgcn_mfma_f32_16x16x32_bf16(            \
                    BREG[j], af[i], acc[i][j], 0, 0, 0);                        \
        __builtin_amdgcn_s_setprio(0);                                          \
        asm volatile("" ::: "memory");                                          \
    }

    for (int kt = 0; kt < nk; kt += 2) {
        // ---- even half: uses A(kt), b0 ----
        if (kt + 2 < nk) stageA((kt + 2) & 3, kt + 2);
#pragma unroll
        for (int j = 0; j < 2; ++j)
            b1[j] = *(const bf16x8*)(Bp[j] + (size_t)(kt + 1) * 512);
        // outstanding allowed: A(kt+1)1 + [A(kt+2)1] + b1 2
        if (kt + 2 < nk) asm volatile("s_waitcnt vmcnt(4)" ::: "memory");
        else             asm volatile("s_waitcnt vmcnt(3)" ::: "memory");
        __builtin_amdgcn_s_barrier();
        asm volatile("" ::: "memory");
        GEMM_HALF(kt, b0);

        // ---- odd half: uses A(kt+1), b1 ----
        if (kt + 3 < nk) stageA((kt + 3) & 3, kt + 3);
        if (kt + 2 < nk) {
#pragma unroll
            for (int j = 0; j < 2; ++j)
                b0[j] = *(const bf16x8*)(Bp[j] + (size_t)(kt + 2) * 512);
        }
        // outstanding allowed: [A(kt+2)1 + A(kt+3)1 + b0 2] or 0
        if (kt + 3 < nk) asm volatile("s_waitcnt vmcnt(4)" ::: "memory");
        else             asm volatile("s_waitcnt vmcnt(0)" ::: "memory");
        __builtin_amdgcn_s_barrier();
        asm volatile("" ::: "memory");
        GEMM_HALF(kt + 1, b1);
    }
#undef GEMM_HALF

    const int l15 = lane & 15, lhi = lane >> 4;

    if (OUT_MODE == 3) {
        // tile rows = 2 graphs (32 each): i<2 -> graph by*2, i>=2 -> by*2+1
        float p0 = 0.f, p1 = 0.f;
#pragma unroll
        for (int i = 0; i < 4; ++i) {
            int e = (i & 1) * 16 + l15;
#pragma unroll
            for (int j = 0; j < 2; ++j) {
                int n = bn + wid * 32 + j * 16 + lhi * 4;
                float4 bv = *(const float4*)(bias + n);
#pragma unroll
                for (int r = 0; r < 4; ++r) {
                    float v = fmaxf(acc[i][j][r] + ((const float*)&bv)[r], 0.f);
                    float wl = wlin[(n + r) * 32 + e];
                    if (i < 2) p0 += v * wl; else p1 += v * wl;
                }
            }
        }
#pragma unroll
        for (int off = 32; off > 0; off >>= 1) {
            p0 += __shfl_down(p0, off, 64);
            p1 += __shfl_down(p1, off, 64);
        }
        if (lane == 0) {
            int g = (bm >> 5);
            atomicAdd(&((float*)Cout)[g], p0);
            atomicAdd(&((float*)Cout)[g + 1], p1);
        }
        return;
    }

#pragma unroll
    for (int i = 0; i < 4; ++i) {
        int m = bm + i * 16 + l15;
#pragma unroll
        for (int j = 0; j < 2; ++j) {
            int n = bn + wid * 32 + j * 16 + lhi * 4;
            float4 bv = *(const float4*)(bias + n);
            ushort4 o;
#pragma unroll
            for (int r = 0; r < 4; ++r) {
                float v = acc[i][j][r] + ((const float*)&bv)[r];
                if (ACT == 1) v = fmaxf(v, 0.f);
                if (ACT == 2) v = 1.0f - 2.0f / (__expf(2.0f * v) + 1.0f);
                ((unsigned short*)&o)[r] = f2bf(v);
            }
            if (OUT_MODE == 1) {
                *(ushort4*)((unsigned short*)Cout + (size_t)m * N + n) = o;
            } else {
                size_t prow = (size_t)(((m >> 7) << 5) | (m & 31));
                size_t idx = prow * 2048 + (size_t)(((m >> 5) & 3) * 512 + n);
                *(ushort4*)((unsigned short*)Cout + idx) = o;
            }
        }
    }
}

// ---------------- sigmoid over 512 graph logits --------------------------------
__global__ void sigmoid_k(const float* __restrict__ logits,
                          const float* __restrict__ blin, float* __restrict__ out) {
    int b = blockIdx.x * 256 + threadIdx.x;
    out[b] = 1.0f / (1.0f + expf(-(logits[b] + blin[0])));
}

extern "C" void kernel_launch(void* const* d_in, const int* in_sizes, int n_in,
                              void* d_out, int out_size, void* d_ws, size_t ws_size,
                              hipStream_t stream) {
    const float* x    = (const float*)d_in[0];
    const float* eattr= (const float*)d_in[1];
    const float* w1   = (const float*)d_in[2];
    const float* wg   = (const float*)d_in[3];
    const float* bg   = (const float*)d_in[4];
    const float* wc1  = (const float*)d_in[5];
    const float* bc1  = (const float*)d_in[6];
    const float* wc2  = (const float*)d_in[7];
    const float* bc2  = (const float*)d_in[8];
    const float* wlin = (const float*)d_in[9];
    const float* blin = (const float*)d_in[10];
    const int*   ei   = (const int*)d_in[11];
    const int* esrc = ei;
    const int* edst = ei + N_EDGES;
    float* out = (float*)d_out;

    // workspace layout (bytes, 16B aligned)
    char* ws = (char*)d_ws;
    float*          dinv   = (float*)(ws + 0);          // 262144
    int*            cnt    = (int*)(ws + 262144);       // 262144
    int*            rp     = (int*)(ws + 524288);       // 262160 (65537 ints)
    int*            cursor = (int*)(ws + 786688);       // 262144
    uint2*          ep     = (uint2*)(ws + 1048832);    // 4194304
    __hip_bfloat16* WTpk   = (__hip_bfloat16*)(ws + 5243136);   // 131072
    __hip_bfloat16* ybf    = (__hip_bfloat16*)(ws + 5374208);   // 16777216
    __hip_bfloat16* V      = (__hip_bfloat16*)(ws + 22151424);  // 67108864
    __hip_bfloat16* act1   = (__hip_bfloat16*)(ws + 89260288);  // 16777216
    __hip_bfloat16* wc1pk  = (__hip_bfloat16*)(ws + 106037504); // 2097152
    __hip_bfloat16* wc2pk  = (__hip_bfloat16*)(ws + 108134656); // 262144
    __hip_bfloat16* xbf    = (__hip_bfloat16*)(ws + 108396800); // 16777216
    float*          logits = (float*)(ws + 125174016);  // 2048
    int*            bsum   = (int*)(ws + 125176064);    // 1024
    if (ws_size < (size_t)125177088) return;

    // 1) init
    init_k<<<N_NODES / 256, 256, 0, stream>>>(dinv, cnt, logits);

    // 2) degree + in-degree counts
    deg_cnt_k<<<N_EDGES / 256, 256, 0, stream>>>(edst, eattr, dinv, cnt);

    // 3) hierarchical scan
    scan1_k<<<256, 256, 0, stream>>>(cnt, rp, bsum);
    scan2_k<<<1, 256, 0, stream>>>(bsum, rp);
    scan3_k<<<256, 256, 0, stream>>>(rp, bsum, cursor, dinv, dinv);

    // 4) scatter edges into CSR, packed 8B records
    scatter_k<<<N_EDGES / 256, 256, 0, stream>>>(esrc, edst, eattr, dinv,
                                                 cursor, ep);

    // 5) prep: x->bf16, weights -> packed fragment order
    prep_k<<<9024, 256, 0, stream>>>(x, xbf, wc1, wc1pk, wc2, wc2pk, w1, wg, WTpk);

    // 6) gather SpMM on bf16 x -> ybf (4-deep ILP)
    gather_k<<<N_NODES / 4, 256, 0, stream>>>(rp, ep,
                                              (const unsigned short*)xbf, dinv, ybf);

    // 7) h2 = tanh(y @ W_comb + b_gcn) -> V (bf16, rearranged layout)
    gemm_mfma_k<2, 2, 0><<<dim3(4, 1024), 256, 0, stream>>>(
        ybf, WTpk, bg, V, nullptr, 65536, 512, 128);

    // 8) cnn1: act1 = relu(V @ wc1^T + bc1), XCD-swizzled 1D grid (1024 blocks)
    gemm_mfma_k<1, 1, 4><<<1024, 256, 0, stream>>>(
        V, wc1pk, bc1, act1, nullptr, 16384, 512, 2048);

    // 9) cnn2 + final dot fused
    gemm_mfma_k<1, 3, 0><<<dim3(2, 256), 256, 0, stream>>>(
        act1, wc2pk, bc2, logits, wlin, 16384, 256, 512);

    // 10) sigmoid
    sigmoid_k<<<2, 256, 0, stream>>>(logits, blin, out);
}

// Round 15
// 212.736 us; speedup vs baseline: 1.1917x; 1.1854x over previous
//
#include <hip/hip_runtime.h>
#include <hip/hip_bf16.h>

#define N_NODES 65536
#define N_EDGES 524288

typedef __attribute__((ext_vector_type(8))) short bf16x8;
typedef __attribute__((ext_vector_type(4))) float f32x4;

__device__ __forceinline__ float bf2f(unsigned short u) {
    union { unsigned int i; float f; } v;
    v.i = ((unsigned int)u) << 16;
    return v.f;
}
__device__ __forceinline__ unsigned short f2bf(float f) {
    union { float f; unsigned int i; } v;
    v.f = f;
    unsigned int r = v.i + 0x7fff + ((v.i >> 16) & 1);  // round-to-nearest-even
    return (unsigned short)(r >> 16);
}

// ---------------- init: cnt=0, logits=0 ---------------------------------------
__global__ void init_k(int* __restrict__ cnt, float* __restrict__ logits) {
    int i = blockIdx.x * 256 + threadIdx.x;
    cnt[i] = 0;
    if (i < 512) logits[i] = 0.0f;
}
// in-degree count only (int atomics; float degree comes from CSR row-sum later)
__global__ void cnt_k(const int* __restrict__ dst, int* __restrict__ cnt) {
    int e = blockIdx.x * 256 + threadIdx.x;
    atomicAdd(&cnt[dst[e]], 1);
}

// ------- hierarchical exclusive scan of cnt[65536] -> rp, cursor --------------
__global__ __launch_bounds__(256) void scan1_k(const int* __restrict__ cnt,
                                               int* __restrict__ rp,
                                               int* __restrict__ bsum) {
    __shared__ int s[256];
    int t = threadIdx.x, g = blockIdx.x * 256 + t;
    int v = cnt[g];
    s[t] = v;
    __syncthreads();
    for (int d = 1; d < 256; d <<= 1) {
        int u = (t >= d) ? s[t - d] : 0;
        __syncthreads();
        s[t] += u;
        __syncthreads();
    }
    rp[g] = s[t] - v;
    if (t == 255) bsum[blockIdx.x] = s[255];
}
__global__ __launch_bounds__(256) void scan2_k(int* __restrict__ bsum,
                                               int* __restrict__ rp) {
    __shared__ int s[256];
    int t = threadIdx.x;
    int v = bsum[t];
    s[t] = v;
    __syncthreads();
    for (int d = 1; d < 256; d <<= 1) {
        int u = (t >= d) ? s[t - d] : 0;
        __syncthreads();
        s[t] += u;
        __syncthreads();
    }
    bsum[t] = s[t] - v;
    if (t == 255) rp[65536] = s[255];
}
__global__ __launch_bounds__(256) void scan3_k(int* __restrict__ rp,
                                               const int* __restrict__ bsum,
                                               int* __restrict__ cursor) {
    int t = threadIdx.x, g = blockIdx.x * 256 + t;
    int r = rp[g] + bsum[blockIdx.x];
    rp[g] = r;
    cursor[g] = r;
}

// ------- scatter edges into dst-sorted CSR order, packed (src, w) -------------
__global__ void scatter_k(const int* __restrict__ src, const int* __restrict__ dst,
                          const float* __restrict__ w,
                          int* __restrict__ cursor, uint2* __restrict__ ep) {
    int e = blockIdx.x * 256 + threadIdx.x;
    int pos = atomicAdd(&cursor[dst[e]], 1);
    uint2 p;
    p.x = (unsigned int)src[e];
    p.y = __float_as_uint(w[e]);
    ep[pos] = p;
}

// ------- degree from CSR row-sum (coalesced, no atomics) + dinv ---------------
__global__ void rowsum_k(const int* __restrict__ rp, const uint2* __restrict__ ep,
                         float* __restrict__ dinv) {
    int n = blockIdx.x * 256 + threadIdx.x;
    int beg = rp[n], end = rp[n + 1];
    float s = 1.0f;  // self-loop weight
    for (int i = beg; i < end; ++i) s += __uint_as_float(ep[i].y);
    dinv[n] = rsqrtf(s);
}

// ------- x' = bf16(dinv[row] * x) ---------------------------------------------
__global__ void xscale_k(const float* __restrict__ x, const float* __restrict__ dinv,
                         __hip_bfloat16* __restrict__ xbf) {
    int i = (blockIdx.x * 256 + threadIdx.x) * 4;
    float d = dinv[i >> 7];
    float4 v = *(const float4*)(x + i);
    alignas(8) __hip_bfloat16 tmp[4] = {
        __float2bfloat16(d * v.x), __float2bfloat16(d * v.y),
        __float2bfloat16(d * v.z), __float2bfloat16(d * v.w)};
    *(ushort4*)((unsigned short*)xbf + i) = *(const ushort4*)tmp;
}

// ------- weight prep: f2b(wc1) | f2b(wc2) | wcomb row-major -------------------
__global__ void wprep_k(const float* __restrict__ wc1, __hip_bfloat16* __restrict__ wc1bf,
                        const float* __restrict__ wc2, __hip_bfloat16* __restrict__ wc2bf,
                        const float* __restrict__ w1, const float* __restrict__ wg,
                        __hip_bfloat16* __restrict__ WT) {
    int bid = blockIdx.x;
    if (bid < 1152) {
        const float* in;
        __hip_bfloat16* outp;
        int i;
        if (bid < 1024) { in = wc1; outp = wc1bf; i = bid * 1024 + threadIdx.x * 4; }
        else            { in = wc2; outp = wc2bf; i = (bid - 1024) * 1024 + threadIdx.x * 4; }
        float4 v = *(const float4*)(in + i);
        alignas(8) __hip_bfloat16 tmp[4] = {__float2bfloat16(v.x), __float2bfloat16(v.y),
                                            __float2bfloat16(v.z), __float2bfloat16(v.w)};
        *(ushort4*)((unsigned short*)outp + i) = *(const ushort4*)tmp;
    } else {
        int t = (bid - 1152) * 256 + threadIdx.x;  // 512*128
        int f = t >> 7, c = t & 127;
        float s = 0.f;
#pragma unroll 8
        for (int m = 0; m < 128; ++m) s += w1[c * 128 + m] * wg[m * 512 + f];
        WT[t] = __float2bfloat16(s);  // WT[f*128 + c]
    }
}

// ---------------- gather SpMM, 8-deep ILP pipeline -----------------------------
// one wave per node; lane holds channels [2l, 2l+1]; y = dinv_n*(sum w*x' + x'_n)
__global__ __launch_bounds__(256) void gather_k(const int* __restrict__ rp,
                                                const uint2* __restrict__ ep,
                                                const unsigned short* __restrict__ xbf,
                                                const float* __restrict__ dinv,
                                                __hip_bfloat16* __restrict__ ybf) {
    int n = (blockIdx.x * 256 + threadIdx.x) >> 6;
    int lane = threadIdx.x & 63;
    int beg = rp[n], end = rp[n + 1];
    float accx, accy;
    {
        unsigned int u = *(const unsigned int*)(xbf + (size_t)n * 128 + lane * 2);
        accx = bf2f((unsigned short)(u & 0xffff));
        accy = bf2f((unsigned short)(u >> 16));
    }
    int i = beg;
    for (; i + 8 <= end; i += 8) {
        uint2 p[8];
        unsigned int u[8];
#pragma unroll
        for (int k = 0; k < 8; ++k) p[k] = ep[i + k];
#pragma unroll
        for (int k = 0; k < 8; ++k)
            u[k] = *(const unsigned int*)(xbf + (size_t)p[k].x * 128 + lane * 2);
#pragma unroll
        for (int k = 0; k < 8; ++k) {
            float c = __uint_as_float(p[k].y);
            accx += c * bf2f((unsigned short)(u[k] & 0xffff));
            accy += c * bf2f((unsigned short)(u[k] >> 16));
        }
    }
    for (; i + 4 <= end; i += 4) {
        uint2 p[4];
        unsigned int u[4];
#pragma unroll
        for (int k = 0; k < 4; ++k) p[k] = ep[i + k];
#pragma unroll
        for (int k = 0; k < 4; ++k)
            u[k] = *(const unsigned int*)(xbf + (size_t)p[k].x * 128 + lane * 2);
#pragma unroll
        for (int k = 0; k < 4; ++k) {
            float c = __uint_as_float(p[k].y);
            accx += c * bf2f((unsigned short)(u[k] & 0xffff));
            accy += c * bf2f((unsigned short)(u[k] >> 16));
        }
    }
    for (; i < end; ++i) {
        uint2 p = ep[i];
        unsigned int u = *(const unsigned int*)(xbf + (size_t)p.x * 128 + lane * 2);
        float c = __uint_as_float(p.y);
        accx += c * bf2f((unsigned short)(u & 0xffff));
        accy += c * bf2f((unsigned short)(u >> 16));
    }
    float dn = dinv[n];
    accx *= dn;
    accy *= dn;
    alignas(4) __hip_bfloat16 o[2] = {__float2bfloat16(accx), __float2bfloat16(accy)};
    *(unsigned int*)((unsigned short*)ybf + (size_t)n * 128 + lane * 2) =
        *(const unsigned int*)o;
}

// ---------------- async global -> LDS, 16B per lane ---------------------------
__device__ __forceinline__ void gll16(const void* g, void* l) {
    __builtin_amdgcn_global_load_lds(
        (const __attribute__((address_space(1))) void*)g,
        (__attribute__((address_space(3))) void*)l, 16, 0, 0);
}

// ---------------- bf16 MFMA GEMM: 4-buffer, 3-DEEP prefetch -------------------
// C = act(A @ B^T + bias). A,B staged via gll16 (conflict-free swizzle, verified
// 0 conflicts). Stage issued AFTER the barrier (so writing buf (kt+3)&3 is
// WAR-safe: all waves passed barrier kt => finished kt-1 reads). vmcnt(8/4/0)
// before the barrier waits only for A(kt) (issued 3 iterations earlier ->
// ~3x longer latency cover than the 2-deep variants). One barrier per K-step.
// SWAPPED-OPERAND mfma: lane holds 4 consecutive output cols of one row.
// ACT: 1 relu, 2 tanh(fast). OUT_MODE: 1 bf16 rm, 2 bf16 permute, 3 final dot.
// SWIZ_NTX>0: XCD-chunked 1D grid. Requires nk = K/32 >= 3.
template <int ACT, int OUT_MODE, int SWIZ_NTX>
__global__ __launch_bounds__(256) void gemm_mfma_k(
    const __hip_bfloat16* __restrict__ A, const __hip_bfloat16* __restrict__ B,
    const float* __restrict__ bias, void* __restrict__ Cout,
    const float* __restrict__ wlin, int M, int N, int K) {
    __shared__ char lds[65536];  // 4 bufs x (A 8KB | B 8KB)

    const int tid = threadIdx.x;
    const int lane = tid & 63, wid = tid >> 6;
    int bx, by;
    if (SWIZ_NTX > 0) {
        int orig = blockIdx.x;
        int per = gridDim.x / (8 * SWIZ_NTX);
        int xcd = orig & 7, k = orig >> 3;
        by = xcd * per + k / SWIZ_NTX;
        bx = k % SWIZ_NTX;
    } else {
        bx = blockIdx.x;
        by = blockIdx.y;
    }
    const int bm = by * 128, bn = bx * 128;
    const int wr = wid >> 1, wc = wid & 1;

    const int srow = wid * 16 + (lane >> 2);
    const int skcol = (((lane & 3) ^ ((lane >> 3) & 3))) * 8;
    const __hip_bfloat16* Abase = A + (size_t)(bm + srow) * K + skcol;
    const __hip_bfloat16* Bbase = B + (size_t)(bn + srow) * K + skcol;
    const int ldso = wid * 1024;

    f32x4 acc[4][4] = {};

    const int lrow = lane & 15;
    const int lkb = (((lane >> 4) ^ ((lane >> 1) & 3)) << 4);
    const int nk = K >> 5;

    auto stage = [&](int buf, int kt) {
        char* la = lds + buf * 16384;
        char* lb = la + 8192;
        gll16(Abase + kt * 32,                  la + ldso);
        gll16(Abase + kt * 32 + (size_t)64 * K, la + 4096 + ldso);
        gll16(Bbase + kt * 32,                  lb + ldso);
        gll16(Bbase + kt * 32 + (size_t)64 * K, lb + 4096 + ldso);
    };

    stage(0, 0);
    stage(1, 1);
    stage(2, 2);

    for (int kt = 0; kt < nk; ++kt) {
        int ahead = nk - 1 - kt;  // stages issued beyond kt at wait time
        if (ahead >= 2)      asm volatile("s_waitcnt vmcnt(8)" ::: "memory");
        else if (ahead == 1) asm volatile("s_waitcnt vmcnt(4)" ::: "memory");
        else                 asm volatile("s_waitcnt vmcnt(0)" ::: "memory");
        __builtin_amdgcn_s_barrier();      // all waves' kt-stage now in LDS
        asm volatile("" ::: "memory");
        if (kt + 3 < nk) stage((kt + 3) & 3, kt + 3);  // WAR-safe post-barrier

        const char* la = lds + (kt & 3) * 16384;
        const char* lb = la + 8192;
        bf16x8 af[4], bfr[4];
#pragma unroll
        for (int i = 0; i < 4; ++i)
            af[i] = *(const bf16x8*)(la + (wr * 64 + i * 16 + lrow) * 64 + lkb);
#pragma unroll
        for (int j = 0; j < 4; ++j)
            bfr[j] = *(const bf16x8*)(lb + (wc * 64 + j * 16 + lrow) * 64 + lkb);
        __builtin_amdgcn_s_setprio(1);
#pragma unroll
        for (int i = 0; i < 4; ++i)
#pragma unroll
            for (int j = 0; j < 4; ++j)
                acc[i][j] = __builtin_amdgcn_mfma_f32_16x16x32_bf16(
                    bfr[j], af[i], acc[i][j], 0, 0, 0);  // SWAPPED operands
        __builtin_amdgcn_s_setprio(0);
        asm volatile("" ::: "memory");
    }

    const int l15 = lane & 15, lhi = lane >> 4;

    if (OUT_MODE == 3) {
        // row m = bm+wr*64+i*16+l15 ; col p = bn+wc*64+j*16+lhi*4+r
        float p0 = 0.f, p1 = 0.f;
#pragma unroll
        for (int i = 0; i < 4; ++i) {
            int e = (i & 1) * 16 + l15;  // m & 31
#pragma unroll
            for (int j = 0; j < 4; ++j) {
                int n = bn + wc * 64 + j * 16 + lhi * 4;
                float4 bv = *(const float4*)(bias + n);
#pragma unroll
                for (int r = 0; r < 4; ++r) {
                    float v = fmaxf(acc[i][j][r] + ((const float*)&bv)[r], 0.f);
                    float wl = wlin[(n + r) * 32 + e];
                    if (i < 2) p0 += v * wl; else p1 += v * wl;
                }
            }
        }
#pragma unroll
        for (int off = 32; off > 0; off >>= 1) {
            p0 += __shfl_down(p0, off, 64);
            p1 += __shfl_down(p1, off, 64);
        }
        if (lane == 0) {
            int g = (bm >> 5) + wr * 2;
            atomicAdd(&((float*)Cout)[g], p0);
            atomicAdd(&((float*)Cout)[g + 1], p1);
        }
        return;
    }

#pragma unroll
    for (int i = 0; i < 4; ++i) {
        int m = bm + wr * 64 + i * 16 + l15;
#pragma unroll
        for (int j = 0; j < 4; ++j) {
            int n = bn + wc * 64 + j * 16 + lhi * 4;
            float4 bv = *(const float4*)(bias + n);
            ushort4 o;
#pragma unroll
            for (int r = 0; r < 4; ++r) {
                float v = acc[i][j][r] + ((const float*)&bv)[r];
                if (ACT == 1) v = fmaxf(v, 0.f);
                if (ACT == 2) v = 1.0f - 2.0f / (__expf(2.0f * v) + 1.0f);
                ((unsigned short*)&o)[r] = f2bf(v);
            }
            if (OUT_MODE == 1) {
                *(ushort4*)((unsigned short*)Cout + (size_t)m * N + n) = o;
            } else {
                size_t prow = (size_t)(((m >> 7) << 5) | (m & 31));
                size_t idx = prow * 2048 + (size_t)(((m >> 5) & 3) * 512 + n);
                *(ushort4*)((unsigned short*)Cout + idx) = o;
            }
        }
    }
}

// ---------------- sigmoid over 512 graph logits --------------------------------
__global__ void sigmoid_k(const float* __restrict__ logits,
                          const float* __restrict__ blin, float* __restrict__ out) {
    int b = blockIdx.x * 256 + threadIdx.x;
    out[b] = 1.0f / (1.0f + expf(-(logits[b] + blin[0])));
}

extern "C" void kernel_launch(void* const* d_in, const int* in_sizes, int n_in,
                              void* d_out, int out_size, void* d_ws, size_t ws_size,
                              hipStream_t stream) {
    const float* x    = (const float*)d_in[0];
    const float* eattr= (const float*)d_in[1];
    const float* w1   = (const float*)d_in[2];
    const float* wg   = (const float*)d_in[3];
    const float* bg   = (const float*)d_in[4];
    const float* wc1  = (const float*)d_in[5];
    const float* bc1  = (const float*)d_in[6];
    const float* wc2  = (const float*)d_in[7];
    const float* bc2  = (const float*)d_in[8];
    const float* wlin = (const float*)d_in[9];
    const float* blin = (const float*)d_in[10];
    const int*   ei   = (const int*)d_in[11];
    const int* esrc = ei;
    const int* edst = ei + N_EDGES;
    float* out = (float*)d_out;

    // workspace layout (bytes, 16B aligned)
    char* ws = (char*)d_ws;
    float*          dinv   = (float*)(ws + 0);          // 262144
    int*            cnt    = (int*)(ws + 262144);       // 262144
    int*            rp     = (int*)(ws + 524288);       // 262160 (65537 ints)
    int*            cursor = (int*)(ws + 786688);       // 262144
    uint2*          ep     = (uint2*)(ws + 1048832);    // 4194304 (packed src,w)
    __hip_bfloat16* WTbf   = (__hip_bfloat16*)(ws + 5243136);   // 131072
    __hip_bfloat16* ybf    = (__hip_bfloat16*)(ws + 5374208);   // 16777216
    __hip_bfloat16* V      = (__hip_bfloat16*)(ws + 22151424);  // 67108864
    __hip_bfloat16* act1   = (__hip_bfloat16*)(ws + 89260288);  // 16777216
    __hip_bfloat16* wc1bf  = (__hip_bfloat16*)(ws + 106037504); // 2097152
    __hip_bfloat16* wc2bf  = (__hip_bfloat16*)(ws + 108134656); // 262144
    __hip_bfloat16* xbf    = (__hip_bfloat16*)(ws + 108396800); // 16777216
    float*          logits = (float*)(ws + 125174016);  // 2048
    int*            bsum   = (int*)(ws + 125176064);    // 1024
    if (ws_size < (size_t)125177088) return;

    // 1) init (cnt=0, logits=0)
    init_k<<<N_NODES / 256, 256, 0, stream>>>(cnt, logits);

    // 2) in-degree counts (int atomics only)
    cnt_k<<<N_EDGES / 256, 256, 0, stream>>>(edst, cnt);

    // 3) hierarchical scan -> rp, cursor
    scan1_k<<<256, 256, 0, stream>>>(cnt, rp, bsum);
    scan2_k<<<1, 256, 0, stream>>>(bsum, rp);
    scan3_k<<<256, 256, 0, stream>>>(rp, bsum, cursor);

    // 4) scatter edges into CSR, packed (src, w) 8B records (no dinv dep)
    scatter_k<<<N_EDGES / 256, 256, 0, stream>>>(esrc, edst, eattr, cursor, ep);

    // 5) degree via coalesced CSR row-sum -> dinv
    rowsum_k<<<N_NODES / 256, 256, 0, stream>>>(rp, ep, dinv);

    // 6) weight prep (row-major bf16) + x' = bf16(dinv * x)
    wprep_k<<<1408, 256, 0, stream>>>(wc1, wc1bf, wc2, wc2bf, w1, wg, WTbf);
    xscale_k<<<(N_NODES * 128 / 4) / 256, 256, 0, stream>>>(x, dinv, xbf);

    // 7) gather SpMM (8-deep ILP) -> ybf
    gather_k<<<N_NODES / 4, 256, 0, stream>>>(rp, ep,
                                              (const unsigned short*)xbf, dinv, ybf);

    // 8) h2 = tanh(y @ W_comb + b_gcn) -> V (bf16, rearranged layout)
    gemm_mfma_k<2, 2, 0><<<dim3(4, 512), 256, 0, stream>>>(
        ybf, WTbf, bg, V, nullptr, 65536, 512, 128);

    // 9) cnn1: act1 = relu(V @ wc1^T + bc1), XCD-swizzled 1D grid
    gemm_mfma_k<1, 1, 4><<<512, 256, 0, stream>>>(
        V, wc1bf, bc1, act1, nullptr, 16384, 512, 2048);

    // 10) cnn2 + final dot fused
    gemm_mfma_k<1, 3, 0><<<dim3(2, 128), 256, 0, stream>>>(
        act1, wc2bf, bc2, logits, wlin, 16384, 256, 512);

    // 11) sigmoid
    sigmoid_k<<<2, 256, 0, stream>>>(logits, blin, out);
}